// Round 1
// baseline (524.615 us; speedup 1.0000x reference)
//
#include <hip/hip_runtime.h>

// GCN output = log_softmax(mean_n(x3) @ Wout + bout). All layers are linear
// up to the mean, so we back-propagate the pooling weights through the graph:
//   u2[m] = sum_{e: src=m} norm_e
//   u1[k] = sum_{e: src=k} norm_e * u2[dst_e]
//   u0[j] = sum_{e: src=j} norm_e * u1[dst_e]
//   v0    = sum_j u0[j] * features[j]              (128-vector)
//   v1 = v0@W0 + (sum u1)*b0 ; v2 = v1@W1 + (sum u2)*b1
//   sum_n x3 = v2@W2 + N*b2 ; pooled = sum_n x3 / N
//   out = log_softmax(pooled@Wout + bout)

#define FDIM 128

__global__ void deg_kernel(const int* __restrict__ edges, int E, int M,
                           int* __restrict__ deg) {
  for (int e = blockIdx.x * blockDim.x + threadIdx.x; e < M;
       e += gridDim.x * blockDim.x) {
    int d = (e < E) ? edges[E + e] : (e - E);   // self loop for e >= E
    atomicAdd(&deg[d], 1);
  }
}

__global__ void dinv_kernel(const int* __restrict__ deg,
                            float* __restrict__ dinv, int N) {
  int i = blockIdx.x * blockDim.x + threadIdx.x;
  if (i < N) {
    float d = (float)deg[i];
    dinv[i] = (d > 0.f) ? rsqrtf(d) : 0.f;
  }
}

// val = norm_e * (uin ? uin[dst] : 1);  uout[src] += val;  *ssum += val (opt)
__global__ void upass_kernel(const int* __restrict__ edges, int E, int M,
                             const float* __restrict__ dinv,
                             const float* __restrict__ uin,
                             float* __restrict__ uout,
                             float* __restrict__ ssum) {
  float local = 0.f;
  for (int e = blockIdx.x * blockDim.x + threadIdx.x; e < M;
       e += gridDim.x * blockDim.x) {
    int s, d;
    if (e < E) { s = edges[e]; d = edges[E + e]; }
    else       { s = e - E;    d = s; }
    float v = dinv[s] * dinv[d];
    if (uin) v *= uin[d];
    atomicAdd(&uout[s], v);
    local += v;
  }
  if (ssum) {
    for (int off = 32; off > 0; off >>= 1)
      local += __shfl_down(local, off, 64);
    if ((threadIdx.x & 63) == 0) atomicAdd(ssum, local);
  }
}

// v0[f] = sum_j u0[j] * feat[j][f]
__global__ void v0_kernel(const float* __restrict__ feat,
                          const float* __restrict__ u0,
                          float* __restrict__ v0, int N) {
  int f = threadIdx.x & (FDIM - 1);
  int rlane = threadIdx.x >> 7;              // 0..1 (256 threads = 2 rows)
  float acc = 0.f;
  for (int r = blockIdx.x * 2 + rlane; r < N; r += gridDim.x * 2) {
    acc += u0[r] * feat[(size_t)r * FDIM + f];
  }
  atomicAdd(&v0[f], acc);
}

__global__ void epilogue_kernel(const float* __restrict__ W0, const float* __restrict__ b0,
                                const float* __restrict__ W1, const float* __restrict__ b1,
                                const float* __restrict__ W2, const float* __restrict__ b2,
                                const float* __restrict__ Wout, const float* __restrict__ bout,
                                const float* __restrict__ v0, const float* __restrict__ ssum,
                                float* __restrict__ out, int N) {
  __shared__ float va[FDIM], vb[FDIM], lg[10];
  int f = threadIdx.x;
  va[f] = v0[f];
  __syncthreads();
  float s2 = ssum[0], s1 = ssum[1];
  // v1 = v0@W0 + s1*b0
  float acc = 0.f;
  for (int k = 0; k < FDIM; ++k) acc += va[k] * W0[k * FDIM + f];
  vb[f] = acc + s1 * b0[f];
  __syncthreads();
  // v2 = v1@W1 + s2*b1
  acc = 0.f;
  for (int k = 0; k < FDIM; ++k) acc += vb[k] * W1[k * FDIM + f];
  va[f] = acc + s2 * b1[f];
  __syncthreads();
  // pooled = (v2@W2)/N + b2
  acc = 0.f;
  for (int k = 0; k < FDIM; ++k) acc += va[k] * W2[k * FDIM + f];
  vb[f] = acc / (float)N + b2[f];
  __syncthreads();
  if (f < 10) {
    float a = 0.f;
    for (int k = 0; k < FDIM; ++k) a += vb[k] * Wout[k * 10 + f];
    lg[f] = a + bout[f];
  }
  __syncthreads();
  if (f == 0) {
    float m = lg[0];
    for (int t = 1; t < 10; ++t) m = fmaxf(m, lg[t]);
    float s = 0.f;
    for (int t = 0; t < 10; ++t) s += expf(lg[t] - m);
    float lse = logf(s);
    for (int t = 0; t < 10; ++t) out[t] = lg[t] - m - lse;
  }
}

extern "C" void kernel_launch(void* const* d_in, const int* in_sizes, int n_in,
                              void* d_out, int out_size, void* d_ws, size_t ws_size,
                              hipStream_t stream) {
  const float* feat = (const float*)d_in[0];
  const int*   edges = (const int*)d_in[1];
  const float* W0 = (const float*)d_in[2];
  const float* b0 = (const float*)d_in[3];
  const float* W1 = (const float*)d_in[4];
  const float* b1 = (const float*)d_in[5];
  const float* W2 = (const float*)d_in[6];
  const float* b2 = (const float*)d_in[7];
  const float* Wout = (const float*)d_in[8];
  const float* bout = (const float*)d_in[9];

  const int N = in_sizes[0] / FDIM;   // 50000
  const int E = in_sizes[1] / 2;      // 1.6M
  const int M = E + N;                // edges + self loops

  char* ws = (char*)d_ws;
  size_t nb = ((size_t)N * 4 + 511) & ~(size_t)511;
  int*   deg  = (int*)(ws);
  float* dinv = (float*)(ws + nb);
  float* u2   = (float*)(ws + 2 * nb);
  float* u1   = (float*)(ws + 3 * nb);
  float* u0   = (float*)(ws + 4 * nb);
  float* v0   = (float*)(ws + 5 * nb);
  float* ssum = (float*)(ws + 5 * nb + 1024);  // [0]=sum u2, [1]=sum u1

  // zero deg/u2/u1/u0/v0/ssum every call (ws is not re-poisoned to zero)
  hipMemsetAsync(ws, 0, 5 * nb + 2048, stream);

  deg_kernel<<<2048, 256, 0, stream>>>(edges, E, M, deg);
  dinv_kernel<<<(N + 255) / 256, 256, 0, stream>>>(deg, dinv, N);
  upass_kernel<<<2048, 256, 0, stream>>>(edges, E, M, dinv, nullptr, u2, &ssum[0]);
  upass_kernel<<<2048, 256, 0, stream>>>(edges, E, M, dinv, u2, u1, &ssum[1]);
  upass_kernel<<<2048, 256, 0, stream>>>(edges, E, M, dinv, u1, u0, nullptr);
  v0_kernel<<<512, 256, 0, stream>>>(feat, u0, v0, N);
  epilogue_kernel<<<1, 128, 0, stream>>>(W0, b0, W1, b1, W2, b2, Wout, bout,
                                         v0, ssum, (float*)d_out, N);
}

// Round 2
// 377.032 us; speedup vs baseline: 1.3914x; 1.3914x over previous
//
#include <hip/hip_runtime.h>

// GCN output = log_softmax(mean_n(x3) @ Wout + bout). All layers are linear
// up to the mean, so we back-propagate the pooling weights through the graph:
//   u2[m] = sum_{e: src=m} norm_e
//   u1[k] = sum_{e: src=k} norm_e * u2[dst_e]
//   u0[j] = sum_{e: src=j} norm_e * u1[dst_e]
//   v0    = sum_j u0[j] * features[j]              (128-vector)
//   v1 = v0@W0 + (sum u1)*b0 ; v2 = v1@W1 + (sum u2)*b1
//   sum_n x3 = v2@W2 + N*b2 ; pooled = sum_n x3 / N
//   out = log_softmax(pooled@Wout + bout)
//
// R2: fp32 global atomicAdd measured at only ~10.6 G/s (155 us/pass, 32B
// write-through per atomic). int atomics (deg pass) run ~4x faster on the
// same address pattern -> accumulate u2/u1/u0 in fixed-point int32 (2^24).

#define FDIM 128
#define S_FIX 16777216.0f           // 2^24
#define INV_S (1.0f / 16777216.0f)

__global__ void deg_kernel(const int* __restrict__ edges, int E, int M,
                           int* __restrict__ deg) {
  for (int e = blockIdx.x * blockDim.x + threadIdx.x; e < M;
       e += gridDim.x * blockDim.x) {
    int d = (e < E) ? edges[E + e] : (e - E);   // self loop for e >= E
    atomicAdd(&deg[d], 1);
  }
}

__global__ void dinv_kernel(const int* __restrict__ deg,
                            float* __restrict__ dinv, int N) {
  int i = blockIdx.x * blockDim.x + threadIdx.x;
  if (i < N) {
    float d = (float)deg[i];
    dinv[i] = (d > 0.f) ? rsqrtf(d) : 0.f;
  }
}

// uout_q[src] += round(S_FIX * norm_e * (uin_q ? uin_q[dst]*INV_S : 1))
__global__ void upass_kernel(const int* __restrict__ edges, int E, int M,
                             const float* __restrict__ dinv,
                             const int* __restrict__ uin_q,
                             int* __restrict__ uout_q) {
  for (int e = blockIdx.x * blockDim.x + threadIdx.x; e < M;
       e += gridDim.x * blockDim.x) {
    int s, d;
    if (e < E) { s = edges[e]; d = edges[E + e]; }
    else       { s = e - E;    d = s; }
    float v = dinv[s] * dinv[d];
    if (uin_q) v *= (float)uin_q[d] * INV_S;
    atomicAdd(&uout_q[s], __float2int_rn(v * S_FIX));
  }
}

// ssum[0] = sum u2, ssum[1] = sum u1
__global__ void sums_kernel(const int* __restrict__ u2q,
                            const int* __restrict__ u1q,
                            float* __restrict__ ssum, int N) {
  int i = blockIdx.x * blockDim.x + threadIdx.x;
  float a = 0.f, b = 0.f;
  if (i < N) { a = (float)u2q[i] * INV_S; b = (float)u1q[i] * INV_S; }
  for (int off = 32; off > 0; off >>= 1) {
    a += __shfl_down(a, off, 64);
    b += __shfl_down(b, off, 64);
  }
  if ((threadIdx.x & 63) == 0) {
    atomicAdd(&ssum[0], a);
    atomicAdd(&ssum[1], b);
  }
}

// v0[f] = sum_j (u0q[j]*INV_S) * feat[j][f]
__global__ void v0_kernel(const float* __restrict__ feat,
                          const int* __restrict__ u0q,
                          float* __restrict__ v0, int N) {
  int f = threadIdx.x & (FDIM - 1);
  int rlane = threadIdx.x >> 7;              // 0..1 (256 threads = 2 rows)
  float acc = 0.f;
  for (int r = blockIdx.x * 2 + rlane; r < N; r += gridDim.x * 2) {
    acc += ((float)u0q[r] * INV_S) * feat[(size_t)r * FDIM + f];
  }
  atomicAdd(&v0[f], acc);
}

__global__ void epilogue_kernel(const float* __restrict__ W0, const float* __restrict__ b0,
                                const float* __restrict__ W1, const float* __restrict__ b1,
                                const float* __restrict__ W2, const float* __restrict__ b2,
                                const float* __restrict__ Wout, const float* __restrict__ bout,
                                const float* __restrict__ v0, const float* __restrict__ ssum,
                                float* __restrict__ out, int N) {
  __shared__ float va[FDIM], vb[FDIM], lg[10];
  int f = threadIdx.x;
  va[f] = v0[f];
  __syncthreads();
  float s2 = ssum[0], s1 = ssum[1];
  // v1 = v0@W0 + s1*b0
  float acc = 0.f;
  for (int k = 0; k < FDIM; ++k) acc += va[k] * W0[k * FDIM + f];
  vb[f] = acc + s1 * b0[f];
  __syncthreads();
  // v2 = v1@W1 + s2*b1
  acc = 0.f;
  for (int k = 0; k < FDIM; ++k) acc += vb[k] * W1[k * FDIM + f];
  va[f] = acc + s2 * b1[f];
  __syncthreads();
  // pooled = (v2@W2)/N + b2
  acc = 0.f;
  for (int k = 0; k < FDIM; ++k) acc += va[k] * W2[k * FDIM + f];
  vb[f] = acc / (float)N + b2[f];
  __syncthreads();
  if (f < 10) {
    float a = 0.f;
    for (int k = 0; k < FDIM; ++k) a += vb[k] * Wout[k * 10 + f];
    lg[f] = a + bout[f];
  }
  __syncthreads();
  if (f == 0) {
    float m = lg[0];
    for (int t = 1; t < 10; ++t) m = fmaxf(m, lg[t]);
    float s = 0.f;
    for (int t = 0; t < 10; ++t) s += expf(lg[t] - m);
    float lse = logf(s);
    for (int t = 0; t < 10; ++t) out[t] = lg[t] - m - lse;
  }
}

extern "C" void kernel_launch(void* const* d_in, const int* in_sizes, int n_in,
                              void* d_out, int out_size, void* d_ws, size_t ws_size,
                              hipStream_t stream) {
  const float* feat = (const float*)d_in[0];
  const int*   edges = (const int*)d_in[1];
  const float* W0 = (const float*)d_in[2];
  const float* b0 = (const float*)d_in[3];
  const float* W1 = (const float*)d_in[4];
  const float* b1 = (const float*)d_in[5];
  const float* W2 = (const float*)d_in[6];
  const float* b2 = (const float*)d_in[7];
  const float* Wout = (const float*)d_in[8];
  const float* bout = (const float*)d_in[9];

  const int N = in_sizes[0] / FDIM;   // 50000
  const int E = in_sizes[1] / 2;      // 1.6M
  const int M = E + N;                // edges + self loops

  char* ws = (char*)d_ws;
  size_t nb = ((size_t)N * 4 + 511) & ~(size_t)511;
  int*   deg  = (int*)(ws);
  float* dinv = (float*)(ws + nb);
  int*   u2q  = (int*)(ws + 2 * nb);
  int*   u1q  = (int*)(ws + 3 * nb);
  int*   u0q  = (int*)(ws + 4 * nb);
  float* v0   = (float*)(ws + 5 * nb);
  float* ssum = (float*)(ws + 5 * nb + 1024);  // [0]=sum u2, [1]=sum u1

  // zero deg/u2q/u1q/u0q/v0/ssum every call (ws is not re-poisoned to zero)
  hipMemsetAsync(ws, 0, 5 * nb + 2048, stream);

  deg_kernel<<<2048, 256, 0, stream>>>(edges, E, M, deg);
  dinv_kernel<<<(N + 255) / 256, 256, 0, stream>>>(deg, dinv, N);
  upass_kernel<<<2048, 256, 0, stream>>>(edges, E, M, dinv, nullptr, u2q);
  upass_kernel<<<2048, 256, 0, stream>>>(edges, E, M, dinv, u2q, u1q);
  upass_kernel<<<2048, 256, 0, stream>>>(edges, E, M, dinv, u1q, u0q);
  sums_kernel<<<(N + 255) / 256, 256, 0, stream>>>(u2q, u1q, ssum, N);
  v0_kernel<<<512, 256, 0, stream>>>(feat, u0q, v0, N);
  epilogue_kernel<<<1, 128, 0, stream>>>(W0, b0, W1, b1, W2, b2, Wout, bout,
                                         v0, ssum, (float*)d_out, N);
}

// Round 3
// 265.380 us; speedup vs baseline: 1.9768x; 1.4207x over previous
//
#include <hip/hip_runtime.h>

// GCN output = log_softmax(mean_n(x3) @ Wout + bout). All layers are linear
// up to the mean, so we back-propagate the pooling weights through the graph:
//   u2 = P^T 1, u1 = P^T u2, u0 = P^T u1   (P = D^-1/2 (A+I) D^-1/2)
//   v0 = sum_j u0[j]*feat[j];  v1 = v0@W0 + (sum u1)*b0
//   v2 = v1@W1 + (sum u2)*b1;  sum x3 = v2@W2 + N*b2; out = logsoftmax(head)
//
// R3: device-scope atomics are the bottleneck (32B write-through RMW at the
// memory-side point, ~21 G/s). Replace scatter with LDS histograms: 4 node
// groups x 50KB LDS, 64 blocks/group partition the edges, per-block partial
// slices written non-atomically, streaming merge. w[d] = dinv[d]*u[d] is
// precomputed in merges so the hist pass does only 2 gathers per edge.

#define FDIM 128
#define HSZ 12500          // nodes per LDS group (50 KB)
#define NBG 64             // blocks per group
#define NB_V0 512
#define S_FIX 16777216.0f
#define INV_S (1.0f / 16777216.0f)

// ---------------- main path: LDS-histogram scatter ----------------

__global__ void __launch_bounds__(1024)
hist_deg_kernel(const int* __restrict__ edges, int E, int e4, int N,
                int* __restrict__ partial) {
  __shared__ int h[HSZ];
  const int g = blockIdx.x / NBG;
  const int j = blockIdx.x - g * NBG;
  const int lo = g * HSZ;
  const int hi = min(N, lo + HSZ);
  const int hs = hi - lo;
  for (int i = threadIdx.x; i < hs; i += blockDim.x) h[i] = 0;
  __syncthreads();
  const int* dst = edges + E;
  const int4* dst4 = (const int4*)dst;
  for (int i = j * blockDim.x + threadIdx.x; i < e4; i += NBG * blockDim.x) {
    int4 d = dst4[i];
    if (d.x >= lo && d.x < hi) atomicAdd(&h[d.x - lo], 1);
    if (d.y >= lo && d.y < hi) atomicAdd(&h[d.y - lo], 1);
    if (d.z >= lo && d.z < hi) atomicAdd(&h[d.z - lo], 1);
    if (d.w >= lo && d.w < hi) atomicAdd(&h[d.w - lo], 1);
  }
  if (j == 0) {
    for (int e = 4 * e4 + threadIdx.x; e < E; e += blockDim.x) {
      int d = dst[e];
      if (d >= lo && d < hi) atomicAdd(&h[d - lo], 1);
    }
  }
  __syncthreads();
  int* out = partial + (size_t)blockIdx.x * HSZ;
  for (int i = threadIdx.x; i < hs; i += blockDim.x) out[i] = h[i];
}

__global__ void merge_dinv_kernel(const int* __restrict__ partial,
                                  float* __restrict__ dinv, int N) {
  int n = blockIdx.x * blockDim.x + threadIdx.x;
  if (n >= N) return;
  int g = n / HSZ;
  int off = n - g * HSZ;
  const int* p = partial + ((size_t)g * NBG) * HSZ + off;
  int s = 1;                                  // self loop
  for (int jj = 0; jj < NBG; ++jj) s += p[(size_t)jj * HSZ];
  dinv[n] = rsqrtf((float)s);
}

// LDS-hist scatter of v = dinv[src]*w[dst] onto src
__global__ void __launch_bounds__(1024)
hist_u_kernel(const int* __restrict__ edges, int E, int e4, int N,
              const float* __restrict__ dinv, const float* __restrict__ w,
              float* __restrict__ partial) {
  __shared__ float h[HSZ];
  const int g = blockIdx.x / NBG;
  const int j = blockIdx.x - g * NBG;
  const int lo = g * HSZ;
  const int hi = min(N, lo + HSZ);
  const int hs = hi - lo;
  for (int i = threadIdx.x; i < hs; i += blockDim.x) h[i] = 0.f;
  __syncthreads();
  const int4* s4 = (const int4*)edges;
  const int4* d4 = (const int4*)(edges + E);
  for (int i = j * blockDim.x + threadIdx.x; i < e4; i += NBG * blockDim.x) {
    int4 s = s4[i];
    int4 d = d4[i];
    if (s.x >= lo && s.x < hi) atomicAdd(&h[s.x - lo], dinv[s.x] * w[d.x]);
    if (s.y >= lo && s.y < hi) atomicAdd(&h[s.y - lo], dinv[s.y] * w[d.y]);
    if (s.z >= lo && s.z < hi) atomicAdd(&h[s.z - lo], dinv[s.z] * w[d.z]);
    if (s.w >= lo && s.w < hi) atomicAdd(&h[s.w - lo], dinv[s.w] * w[d.w]);
  }
  if (j == 0) {
    const int* se = edges; const int* de = edges + E;
    for (int e = 4 * e4 + threadIdx.x; e < E; e += blockDim.x) {
      int s = se[e], d = de[e];
      if (s >= lo && s < hi) atomicAdd(&h[s - lo], dinv[s] * w[d]);
    }
  }
  __syncthreads();
  float* out = partial + (size_t)blockIdx.x * HSZ;
  for (int i = threadIdx.x; i < hs; i += blockDim.x) out[i] = h[i];
}

// uout[n] = sum_j partial[j][n] + dinv[n]*win[n]; wout = dinv*uout; ssum += uout
__global__ void merge_u_kernel(const float* __restrict__ partial,
                               const float* __restrict__ dinv,
                               const float* __restrict__ win,
                               float* __restrict__ uout,
                               float* __restrict__ wout,
                               float* __restrict__ ssum, int N) {
  int n = blockIdx.x * blockDim.x + threadIdx.x;
  float u = 0.f;
  if (n < N) {
    int g = n / HSZ;
    int off = n - g * HSZ;
    const float* p = partial + ((size_t)g * NBG) * HSZ + off;
    for (int jj = 0; jj < NBG; ++jj) u += p[(size_t)jj * HSZ];
    u += dinv[n] * win[n];                    // self loop
    if (uout) uout[n] = u;
    if (wout) wout[n] = dinv[n] * u;
  }
  if (ssum) {
    float a = u;
    for (int o = 32; o > 0; o >>= 1) a += __shfl_down(a, o, 64);
    if ((threadIdx.x & 63) == 0) atomicAdd(ssum, a);
  }
}

// per-block partials of v0[f] = sum_j u0[j]*feat[j][f]
__global__ void v0_kernel(const float* __restrict__ feat,
                          const float* __restrict__ u0,
                          float* __restrict__ v0p, int N) {
  __shared__ float sh[2][FDIM];
  int f = threadIdx.x & (FDIM - 1);
  int r2 = threadIdx.x >> 7;
  float acc = 0.f;
  for (int r = blockIdx.x * 2 + r2; r < N; r += gridDim.x * 2)
    acc += u0[r] * feat[(size_t)r * FDIM + f];
  sh[r2][f] = acc;
  __syncthreads();
  if (r2 == 0) v0p[(size_t)blockIdx.x * FDIM + f] = sh[0][f] + sh[1][f];
}

__global__ void epilogue_kernel(const float* __restrict__ W0, const float* __restrict__ b0,
                                const float* __restrict__ W1, const float* __restrict__ b1,
                                const float* __restrict__ W2, const float* __restrict__ b2,
                                const float* __restrict__ Wout, const float* __restrict__ bout,
                                const float* __restrict__ v0p, int nv0,
                                const float* __restrict__ ssum,
                                float* __restrict__ out, int N) {
  __shared__ float va[FDIM], vb[FDIM], lg[10];
  int f = threadIdx.x;
  float acc = 0.f;
  for (int j = 0; j < nv0; ++j) acc += v0p[(size_t)j * FDIM + f];
  va[f] = acc;
  __syncthreads();
  float s2 = ssum[0], s1 = ssum[1];
  acc = 0.f;
  for (int k = 0; k < FDIM; ++k) acc += va[k] * W0[k * FDIM + f];
  vb[f] = acc + s1 * b0[f];
  __syncthreads();
  acc = 0.f;
  for (int k = 0; k < FDIM; ++k) acc += vb[k] * W1[k * FDIM + f];
  va[f] = acc + s2 * b1[f];
  __syncthreads();
  acc = 0.f;
  for (int k = 0; k < FDIM; ++k) acc += va[k] * W2[k * FDIM + f];
  vb[f] = acc / (float)N + b2[f];
  __syncthreads();
  if (f < 10) {
    float a = 0.f;
    for (int k = 0; k < FDIM; ++k) a += vb[k] * Wout[k * 10 + f];
    lg[f] = a + bout[f];
  }
  __syncthreads();
  if (f == 0) {
    float m = lg[0];
    for (int t = 1; t < 10; ++t) m = fmaxf(m, lg[t]);
    float s = 0.f;
    for (int t = 0; t < 10; ++t) s += expf(lg[t] - m);
    float lse = logf(s);
    for (int t = 0; t < 10; ++t) out[t] = lg[t] - m - lse;
  }
}

// ---------------- fallback path (R2, proven): global atomics ----------------

__global__ void deg_kernel(const int* __restrict__ edges, int E, int M,
                           int* __restrict__ deg) {
  for (int e = blockIdx.x * blockDim.x + threadIdx.x; e < M;
       e += gridDim.x * blockDim.x) {
    int d = (e < E) ? edges[E + e] : (e - E);
    atomicAdd(&deg[d], 1);
  }
}

__global__ void dinv_kernel(const int* __restrict__ deg,
                            float* __restrict__ dinv, int N) {
  int i = blockIdx.x * blockDim.x + threadIdx.x;
  if (i < N) {
    float d = (float)deg[i];
    dinv[i] = (d > 0.f) ? rsqrtf(d) : 0.f;
  }
}

__global__ void upass_kernel(const int* __restrict__ edges, int E, int M,
                             const float* __restrict__ dinv,
                             const int* __restrict__ uin_q,
                             int* __restrict__ uout_q) {
  for (int e = blockIdx.x * blockDim.x + threadIdx.x; e < M;
       e += gridDim.x * blockDim.x) {
    int s, d;
    if (e < E) { s = edges[e]; d = edges[E + e]; }
    else       { s = e - E;    d = s; }
    float v = dinv[s] * dinv[d];
    if (uin_q) v *= (float)uin_q[d] * INV_S;
    atomicAdd(&uout_q[s], __float2int_rn(v * S_FIX));
  }
}

__global__ void sums_kernel(const int* __restrict__ u2q,
                            const int* __restrict__ u1q,
                            float* __restrict__ ssum, int N) {
  int i = blockIdx.x * blockDim.x + threadIdx.x;
  float a = 0.f, b = 0.f;
  if (i < N) { a = (float)u2q[i] * INV_S; b = (float)u1q[i] * INV_S; }
  for (int o = 32; o > 0; o >>= 1) {
    a += __shfl_down(a, o, 64);
    b += __shfl_down(b, o, 64);
  }
  if ((threadIdx.x & 63) == 0) {
    atomicAdd(&ssum[0], a);
    atomicAdd(&ssum[1], b);
  }
}

__global__ void v0_atomic_kernel(const float* __restrict__ feat,
                                 const int* __restrict__ u0q,
                                 float* __restrict__ v0, int N) {
  int f = threadIdx.x & (FDIM - 1);
  int r2 = threadIdx.x >> 7;
  float acc = 0.f;
  for (int r = blockIdx.x * 2 + r2; r < N; r += gridDim.x * 2)
    acc += ((float)u0q[r] * INV_S) * feat[(size_t)r * FDIM + f];
  atomicAdd(&v0[f], acc);
}

// ---------------- launch ----------------

extern "C" void kernel_launch(void* const* d_in, const int* in_sizes, int n_in,
                              void* d_out, int out_size, void* d_ws, size_t ws_size,
                              hipStream_t stream) {
  const float* feat = (const float*)d_in[0];
  const int*   edges = (const int*)d_in[1];
  const float* W0 = (const float*)d_in[2];
  const float* b0 = (const float*)d_in[3];
  const float* W1 = (const float*)d_in[4];
  const float* b1 = (const float*)d_in[5];
  const float* W2 = (const float*)d_in[6];
  const float* b2 = (const float*)d_in[7];
  const float* Wout = (const float*)d_in[8];
  const float* bout = (const float*)d_in[9];

  const int N = in_sizes[0] / FDIM;          // 50000
  const int E = in_sizes[1] / 2;             // 1.6M
  const int NG = (N + HSZ - 1) / HSZ;        // 4 groups
  const int e4 = ((E & 3) == 0) ? (E >> 2) : 0;

  char* ws = (char*)d_ws;
  size_t nb = ((size_t)N * 4 + 511) & ~(size_t)511;
  size_t partB = ((size_t)NG * NBG * HSZ * 4 + 511) & ~(size_t)511;
  size_t v0pB = (size_t)NB_V0 * FDIM * 4;
  size_t need = partB + 4 * nb + v0pB + 512;

  if (ws_size >= need) {
    // main path
    char* p = ws;
    void*  part = (void*)p;        p += partB;
    float* dinv = (float*)p;       p += nb;
    float* w2   = (float*)p;       p += nb;
    float* w1   = (float*)p;       p += nb;
    float* u0   = (float*)p;       p += nb;
    float* v0p  = (float*)p;       p += v0pB;
    float* ssum = (float*)p;       // [0]=sum u2, [1]=sum u1

    hipMemsetAsync(ssum, 0, 256, stream);

    const int mergeGrid = (N + 255) / 256;
    hist_deg_kernel<<<NG * NBG, 1024, 0, stream>>>(edges, E, e4, N, (int*)part);
    merge_dinv_kernel<<<mergeGrid, 256, 0, stream>>>((const int*)part, dinv, N);
    hist_u_kernel<<<NG * NBG, 1024, 0, stream>>>(edges, E, e4, N, dinv, dinv, (float*)part);
    merge_u_kernel<<<mergeGrid, 256, 0, stream>>>((const float*)part, dinv, dinv,
                                                  nullptr, w2, &ssum[0], N);
    hist_u_kernel<<<NG * NBG, 1024, 0, stream>>>(edges, E, e4, N, dinv, w2, (float*)part);
    merge_u_kernel<<<mergeGrid, 256, 0, stream>>>((const float*)part, dinv, w2,
                                                  nullptr, w1, &ssum[1], N);
    hist_u_kernel<<<NG * NBG, 1024, 0, stream>>>(edges, E, e4, N, dinv, w1, (float*)part);
    merge_u_kernel<<<mergeGrid, 256, 0, stream>>>((const float*)part, dinv, w1,
                                                  u0, nullptr, nullptr, N);
    v0_kernel<<<NB_V0, 256, 0, stream>>>(feat, u0, v0p, N);
    epilogue_kernel<<<1, 128, 0, stream>>>(W0, b0, W1, b1, W2, b2, Wout, bout,
                                           v0p, NB_V0, ssum, (float*)d_out, N);
  } else {
    // fallback (R2): global-atomic scatter
    const int M = E + N;
    int*   deg  = (int*)(ws);
    float* dinv = (float*)(ws + nb);
    int*   u2q  = (int*)(ws + 2 * nb);
    int*   u1q  = (int*)(ws + 3 * nb);
    int*   u0q  = (int*)(ws + 4 * nb);
    float* v0   = (float*)(ws + 5 * nb);
    float* ssum = (float*)(ws + 5 * nb + 1024);

    hipMemsetAsync(ws, 0, 5 * nb + 2048, stream);

    deg_kernel<<<2048, 256, 0, stream>>>(edges, E, M, deg);
    dinv_kernel<<<(N + 255) / 256, 256, 0, stream>>>(deg, dinv, N);
    upass_kernel<<<2048, 256, 0, stream>>>(edges, E, M, dinv, nullptr, u2q);
    upass_kernel<<<2048, 256, 0, stream>>>(edges, E, M, dinv, u2q, u1q);
    upass_kernel<<<2048, 256, 0, stream>>>(edges, E, M, dinv, u1q, u0q);
    sums_kernel<<<(N + 255) / 256, 256, 0, stream>>>(u2q, u1q, ssum, N);
    v0_atomic_kernel<<<512, 256, 0, stream>>>(feat, u0q, v0, N);
    epilogue_kernel<<<1, 128, 0, stream>>>(W0, b0, W1, b1, W2, b2, Wout, bout,
                                           v0, 1, ssum, (float*)d_out, N);
  }
}

// Round 4
// 160.934 us; speedup vs baseline: 3.2598x; 1.6490x over previous
//
#include <hip/hip_runtime.h>

// GCN output = log_softmax(mean_n(x3) @ Wout + bout). All layers are linear
// up to the mean, so we back-propagate the pooling weights through the graph:
//   u2 = P^T 1, u1 = P^T u2, u0 = P^T u1   (P = D^-1/2 (A+I) D^-1/2)
//   v0 = sum_j u0[j]*feat[j];  v1 = v0@W0 + (sum u1)*b0
//   v2 = v1@W1 + (sum u2)*b1;  sum x3 = v2@W2 + N*b2; out = logsoftmax(head)
//
// R3: LDS-histogram scatter replaced global atomics (atomic RMW ~21 G/s cap).
// R4: old 128-thread epilogue was 140 us (2 waves, latency-bound serial W
// loads). New final_kernel: 1024 threads, W staged to LDS via float4, K
// split 8-way + LDS tree reduce.

#define FDIM 128
#define HSZ 12500          // nodes per LDS group (50 KB)
#define NBG 64             // blocks per group
#define NB_V0 512
#define S_FIX 16777216.0f
#define INV_S (1.0f / 16777216.0f)

// ---------------- main path: LDS-histogram scatter ----------------

__global__ void __launch_bounds__(1024)
hist_deg_kernel(const int* __restrict__ edges, int E, int e4, int N,
                int* __restrict__ partial) {
  __shared__ int h[HSZ];
  const int g = blockIdx.x / NBG;
  const int j = blockIdx.x - g * NBG;
  const int lo = g * HSZ;
  const int hi = min(N, lo + HSZ);
  const int hs = hi - lo;
  for (int i = threadIdx.x; i < hs; i += blockDim.x) h[i] = 0;
  __syncthreads();
  const int* dst = edges + E;
  const int4* dst4 = (const int4*)dst;
  for (int i = j * blockDim.x + threadIdx.x; i < e4; i += NBG * blockDim.x) {
    int4 d = dst4[i];
    if (d.x >= lo && d.x < hi) atomicAdd(&h[d.x - lo], 1);
    if (d.y >= lo && d.y < hi) atomicAdd(&h[d.y - lo], 1);
    if (d.z >= lo && d.z < hi) atomicAdd(&h[d.z - lo], 1);
    if (d.w >= lo && d.w < hi) atomicAdd(&h[d.w - lo], 1);
  }
  if (j == 0) {
    for (int e = 4 * e4 + threadIdx.x; e < E; e += blockDim.x) {
      int d = dst[e];
      if (d >= lo && d < hi) atomicAdd(&h[d - lo], 1);
    }
  }
  __syncthreads();
  int* out = partial + (size_t)blockIdx.x * HSZ;
  for (int i = threadIdx.x; i < hs; i += blockDim.x) out[i] = h[i];
}

__global__ void merge_dinv_kernel(const int* __restrict__ partial,
                                  float* __restrict__ dinv, int N) {
  int n = blockIdx.x * blockDim.x + threadIdx.x;
  if (n >= N) return;
  int g = n / HSZ;
  int off = n - g * HSZ;
  const int* p = partial + ((size_t)g * NBG) * HSZ + off;
  int s = 1;                                  // self loop
  for (int jj = 0; jj < NBG; ++jj) s += p[(size_t)jj * HSZ];
  dinv[n] = rsqrtf((float)s);
}

// LDS-hist scatter of v = dinv[src]*w[dst] onto src
__global__ void __launch_bounds__(1024)
hist_u_kernel(const int* __restrict__ edges, int E, int e4, int N,
              const float* __restrict__ dinv, const float* __restrict__ w,
              float* __restrict__ partial) {
  __shared__ float h[HSZ];
  const int g = blockIdx.x / NBG;
  const int j = blockIdx.x - g * NBG;
  const int lo = g * HSZ;
  const int hi = min(N, lo + HSZ);
  const int hs = hi - lo;
  for (int i = threadIdx.x; i < hs; i += blockDim.x) h[i] = 0.f;
  __syncthreads();
  const int4* s4 = (const int4*)edges;
  const int4* d4 = (const int4*)(edges + E);
  for (int i = j * blockDim.x + threadIdx.x; i < e4; i += NBG * blockDim.x) {
    int4 s = s4[i];
    int4 d = d4[i];
    if (s.x >= lo && s.x < hi) atomicAdd(&h[s.x - lo], dinv[s.x] * w[d.x]);
    if (s.y >= lo && s.y < hi) atomicAdd(&h[s.y - lo], dinv[s.y] * w[d.y]);
    if (s.z >= lo && s.z < hi) atomicAdd(&h[s.z - lo], dinv[s.z] * w[d.z]);
    if (s.w >= lo && s.w < hi) atomicAdd(&h[s.w - lo], dinv[s.w] * w[d.w]);
  }
  if (j == 0) {
    const int* se = edges; const int* de = edges + E;
    for (int e = 4 * e4 + threadIdx.x; e < E; e += blockDim.x) {
      int s = se[e], d = de[e];
      if (s >= lo && s < hi) atomicAdd(&h[s - lo], dinv[s] * w[d]);
    }
  }
  __syncthreads();
  float* out = partial + (size_t)blockIdx.x * HSZ;
  for (int i = threadIdx.x; i < hs; i += blockDim.x) out[i] = h[i];
}

// uout[n] = sum_j partial[j][n] + dinv[n]*win[n]; wout = dinv*uout; ssum += uout
__global__ void merge_u_kernel(const float* __restrict__ partial,
                               const float* __restrict__ dinv,
                               const float* __restrict__ win,
                               float* __restrict__ uout,
                               float* __restrict__ wout,
                               float* __restrict__ ssum, int N) {
  int n = blockIdx.x * blockDim.x + threadIdx.x;
  float u = 0.f;
  if (n < N) {
    int g = n / HSZ;
    int off = n - g * HSZ;
    const float* p = partial + ((size_t)g * NBG) * HSZ + off;
    for (int jj = 0; jj < NBG; ++jj) u += p[(size_t)jj * HSZ];
    u += dinv[n] * win[n];                    // self loop
    if (uout) uout[n] = u;
    if (wout) wout[n] = dinv[n] * u;
  }
  if (ssum) {
    float a = u;
    for (int o = 32; o > 0; o >>= 1) a += __shfl_down(a, o, 64);
    if ((threadIdx.x & 63) == 0) atomicAdd(ssum, a);
  }
}

// per-block partials of v0[f] = sum_j u0[j]*feat[j][f]
__global__ void v0_kernel(const float* __restrict__ feat,
                          const float* __restrict__ u0,
                          float* __restrict__ v0p, int N) {
  __shared__ float sh[2][FDIM];
  int f = threadIdx.x & (FDIM - 1);
  int r2 = threadIdx.x >> 7;
  float acc = 0.f;
  for (int r = blockIdx.x * 2 + r2; r < N; r += gridDim.x * 2)
    acc += u0[r] * feat[(size_t)r * FDIM + f];
  sh[r2][f] = acc;
  __syncthreads();
  if (r2 == 0) v0p[(size_t)blockIdx.x * FDIM + f] = sh[0][f] + sh[1][f];
}

// 1024-thread tail: reduce v0p, 3 matvecs with W staged in LDS, head+softmax
__global__ void __launch_bounds__(1024)
final_kernel(const float* __restrict__ W0, const float* __restrict__ b0,
             const float* __restrict__ W1, const float* __restrict__ b1,
             const float* __restrict__ W2, const float* __restrict__ b2,
             const float* __restrict__ Wout, const float* __restrict__ bout,
             const float* __restrict__ v0p, int nv0,
             const float* __restrict__ ssum,
             float* __restrict__ out, int N) {
  __shared__ float Wl[FDIM * FDIM];          // 64 KB
  __shared__ float va[FDIM], vb[FDIM];
  __shared__ float part[8][FDIM];
  __shared__ float lg[10];
  const int t = threadIdx.x;
  const int f = t & (FDIM - 1);
  const int sl = t >> 7;                     // 0..7

  // stage W0 into LDS (pipelines with the v0p reduction below)
  {
    const float4* w4 = (const float4*)W0;
    float4* l4 = (float4*)Wl;
    #pragma unroll
    for (int i = 0; i < 4; ++i) l4[t + i * 1024] = w4[t + i * 1024];
  }
  // reduce v0p: 8 slices of 64 rows each
  float acc = 0.f;
  for (int j = sl; j < nv0; j += 8) acc += v0p[(size_t)j * FDIM + f];
  part[sl][f] = acc;
  __syncthreads();
  if (sl == 0) {
    float s = 0.f;
    #pragma unroll
    for (int j = 0; j < 8; ++j) s += part[j][f];
    va[f] = s;
  }
  __syncthreads();

  const float s2 = ssum[0], s1 = ssum[1];

  // vb = va@W0 + s1*b0
  acc = 0.f;
  #pragma unroll
  for (int k = 0; k < 16; ++k) {
    int kk = sl * 16 + k;
    acc += va[kk] * Wl[kk * FDIM + f];
  }
  part[sl][f] = acc;
  __syncthreads();                            // also: all Wl reads done
  {
    const float4* w4 = (const float4*)W1;     // stage W1
    float4* l4 = (float4*)Wl;
    #pragma unroll
    for (int i = 0; i < 4; ++i) l4[t + i * 1024] = w4[t + i * 1024];
  }
  if (sl == 0) {
    float s = 0.f;
    #pragma unroll
    for (int j = 0; j < 8; ++j) s += part[j][f];
    vb[f] = s + s1 * b0[f];
  }
  __syncthreads();

  // va = vb@W1 + s2*b1
  acc = 0.f;
  #pragma unroll
  for (int k = 0; k < 16; ++k) {
    int kk = sl * 16 + k;
    acc += vb[kk] * Wl[kk * FDIM + f];
  }
  part[sl][f] = acc;
  __syncthreads();
  {
    const float4* w4 = (const float4*)W2;     // stage W2
    float4* l4 = (float4*)Wl;
    #pragma unroll
    for (int i = 0; i < 4; ++i) l4[t + i * 1024] = w4[t + i * 1024];
  }
  if (sl == 0) {
    float s = 0.f;
    #pragma unroll
    for (int j = 0; j < 8; ++j) s += part[j][f];
    va[f] = s + s2 * b1[f];
  }
  __syncthreads();

  // vb = (va@W2)/N + b2  (= pooled)
  acc = 0.f;
  #pragma unroll
  for (int k = 0; k < 16; ++k) {
    int kk = sl * 16 + k;
    acc += va[kk] * Wl[kk * FDIM + f];
  }
  part[sl][f] = acc;
  __syncthreads();
  if (sl == 0) {
    float s = 0.f;
    #pragma unroll
    for (int j = 0; j < 8; ++j) s += part[j][f];
    vb[f] = s / (float)N + b2[f];
  }
  __syncthreads();

  if (t < 10) {
    float a = 0.f;
    for (int k = 0; k < FDIM; ++k) a += vb[k] * Wout[k * 10 + t];
    lg[t] = a + bout[t];
  }
  __syncthreads();
  if (t == 0) {
    float m = lg[0];
    for (int q = 1; q < 10; ++q) m = fmaxf(m, lg[q]);
    float s = 0.f;
    for (int q = 0; q < 10; ++q) s += expf(lg[q] - m);
    float lse = logf(s);
    for (int q = 0; q < 10; ++q) out[q] = lg[q] - m - lse;
  }
}

// ---------------- fallback path (R2, proven): global atomics ----------------

__global__ void deg_kernel(const int* __restrict__ edges, int E, int M,
                           int* __restrict__ deg) {
  for (int e = blockIdx.x * blockDim.x + threadIdx.x; e < M;
       e += gridDim.x * blockDim.x) {
    int d = (e < E) ? edges[E + e] : (e - E);
    atomicAdd(&deg[d], 1);
  }
}

__global__ void dinv_kernel(const int* __restrict__ deg,
                            float* __restrict__ dinv, int N) {
  int i = blockIdx.x * blockDim.x + threadIdx.x;
  if (i < N) {
    float d = (float)deg[i];
    dinv[i] = (d > 0.f) ? rsqrtf(d) : 0.f;
  }
}

__global__ void upass_kernel(const int* __restrict__ edges, int E, int M,
                             const float* __restrict__ dinv,
                             const int* __restrict__ uin_q,
                             int* __restrict__ uout_q) {
  for (int e = blockIdx.x * blockDim.x + threadIdx.x; e < M;
       e += gridDim.x * blockDim.x) {
    int s, d;
    if (e < E) { s = edges[e]; d = edges[E + e]; }
    else       { s = e - E;    d = s; }
    float v = dinv[s] * dinv[d];
    if (uin_q) v *= (float)uin_q[d] * INV_S;
    atomicAdd(&uout_q[s], __float2int_rn(v * S_FIX));
  }
}

__global__ void sums_kernel(const int* __restrict__ u2q,
                            const int* __restrict__ u1q,
                            float* __restrict__ ssum, int N) {
  int i = blockIdx.x * blockDim.x + threadIdx.x;
  float a = 0.f, b = 0.f;
  if (i < N) { a = (float)u2q[i] * INV_S; b = (float)u1q[i] * INV_S; }
  for (int o = 32; o > 0; o >>= 1) {
    a += __shfl_down(a, o, 64);
    b += __shfl_down(b, o, 64);
  }
  if ((threadIdx.x & 63) == 0) {
    atomicAdd(&ssum[0], a);
    atomicAdd(&ssum[1], b);
  }
}

__global__ void v0_atomic_kernel(const float* __restrict__ feat,
                                 const int* __restrict__ u0q,
                                 float* __restrict__ v0, int N) {
  int f = threadIdx.x & (FDIM - 1);
  int r2 = threadIdx.x >> 7;
  float acc = 0.f;
  for (int r = blockIdx.x * 2 + r2; r < N; r += gridDim.x * 2)
    acc += ((float)u0q[r] * INV_S) * feat[(size_t)r * FDIM + f];
  atomicAdd(&v0[f], acc);
}

// ---------------- launch ----------------

extern "C" void kernel_launch(void* const* d_in, const int* in_sizes, int n_in,
                              void* d_out, int out_size, void* d_ws, size_t ws_size,
                              hipStream_t stream) {
  const float* feat = (const float*)d_in[0];
  const int*   edges = (const int*)d_in[1];
  const float* W0 = (const float*)d_in[2];
  const float* b0 = (const float*)d_in[3];
  const float* W1 = (const float*)d_in[4];
  const float* b1 = (const float*)d_in[5];
  const float* W2 = (const float*)d_in[6];
  const float* b2 = (const float*)d_in[7];
  const float* Wout = (const float*)d_in[8];
  const float* bout = (const float*)d_in[9];

  const int N = in_sizes[0] / FDIM;          // 50000
  const int E = in_sizes[1] / 2;             // 1.6M
  const int NG = (N + HSZ - 1) / HSZ;        // 4 groups
  const int e4 = ((E & 3) == 0) ? (E >> 2) : 0;

  char* ws = (char*)d_ws;
  size_t nb = ((size_t)N * 4 + 511) & ~(size_t)511;
  size_t partB = ((size_t)NG * NBG * HSZ * 4 + 511) & ~(size_t)511;
  size_t v0pB = (size_t)NB_V0 * FDIM * 4;
  size_t need = partB + 4 * nb + v0pB + 512;

  if (ws_size >= need) {
    // main path
    char* p = ws;
    void*  part = (void*)p;        p += partB;
    float* dinv = (float*)p;       p += nb;
    float* w2   = (float*)p;       p += nb;
    float* w1   = (float*)p;       p += nb;
    float* u0   = (float*)p;       p += nb;
    float* v0p  = (float*)p;       p += v0pB;
    float* ssum = (float*)p;       // [0]=sum u2, [1]=sum u1

    hipMemsetAsync(ssum, 0, 256, stream);

    const int mergeGrid = (N + 255) / 256;
    hist_deg_kernel<<<NG * NBG, 1024, 0, stream>>>(edges, E, e4, N, (int*)part);
    merge_dinv_kernel<<<mergeGrid, 256, 0, stream>>>((const int*)part, dinv, N);
    hist_u_kernel<<<NG * NBG, 1024, 0, stream>>>(edges, E, e4, N, dinv, dinv, (float*)part);
    merge_u_kernel<<<mergeGrid, 256, 0, stream>>>((const float*)part, dinv, dinv,
                                                  nullptr, w2, &ssum[0], N);
    hist_u_kernel<<<NG * NBG, 1024, 0, stream>>>(edges, E, e4, N, dinv, w2, (float*)part);
    merge_u_kernel<<<mergeGrid, 256, 0, stream>>>((const float*)part, dinv, w2,
                                                  nullptr, w1, &ssum[1], N);
    hist_u_kernel<<<NG * NBG, 1024, 0, stream>>>(edges, E, e4, N, dinv, w1, (float*)part);
    merge_u_kernel<<<mergeGrid, 256, 0, stream>>>((const float*)part, dinv, w1,
                                                  u0, nullptr, nullptr, N);
    v0_kernel<<<NB_V0, 256, 0, stream>>>(feat, u0, v0p, N);
    final_kernel<<<1, 1024, 0, stream>>>(W0, b0, W1, b1, W2, b2, Wout, bout,
                                         v0p, NB_V0, ssum, (float*)d_out, N);
  } else {
    // fallback (R2): global-atomic scatter
    const int M = E + N;
    int*   deg  = (int*)(ws);
    float* dinv = (float*)(ws + nb);
    int*   u2q  = (int*)(ws + 2 * nb);
    int*   u1q  = (int*)(ws + 3 * nb);
    int*   u0q  = (int*)(ws + 4 * nb);
    float* v0   = (float*)(ws + 5 * nb);
    float* ssum = (float*)(ws + 5 * nb + 1024);

    hipMemsetAsync(ws, 0, 5 * nb + 2048, stream);

    deg_kernel<<<2048, 256, 0, stream>>>(edges, E, M, deg);
    dinv_kernel<<<(N + 255) / 256, 256, 0, stream>>>(deg, dinv, N);
    upass_kernel<<<2048, 256, 0, stream>>>(edges, E, M, dinv, nullptr, u2q);
    upass_kernel<<<2048, 256, 0, stream>>>(edges, E, M, dinv, u2q, u1q);
    upass_kernel<<<2048, 256, 0, stream>>>(edges, E, M, dinv, u1q, u0q);
    sums_kernel<<<(N + 255) / 256, 256, 0, stream>>>(u2q, u1q, ssum, N);
    v0_atomic_kernel<<<512, 256, 0, stream>>>(feat, u0q, v0, N);
    final_kernel<<<1, 1024, 0, stream>>>(W0, b0, W1, b1, W2, b2, Wout, bout,
                                         v0, 1, ssum, (float*)d_out, N);
  }
}

// Round 5
// 125.294 us; speedup vs baseline: 4.1871x; 1.2845x over previous
//
#include <hip/hip_runtime.h>

// GCN output = log_softmax(mean_n(x3) @ Wout + bout). All layers are linear
// up to the mean, so we back-propagate the pooling weights through the graph:
//   u2 = P^T 1, u1 = P^T u2, u0 = P^T u1   (P = D^-1/2 (A+I) D^-1/2)
//   v0 = sum_j u0[j]*feat[j];  v1 = v0@W0 + (sum u1)*b0
//   v2 = v1@W1 + (sum u2)*b1;  sum x3 = v2@W2 + N*b2; out = logsoftmax(head)
//
// R3: LDS-histogram scatter replaced global atomics (atomic RMW ~21 G/s cap).
// R4: 1024-thread final_kernel (W staged in LDS) replaced the 140 us
//     latency-bound 128-thread epilogue.
// R5: (a) no memset / no device atomics anywhere: merge_u writes per-block
//     partial sums, final_kernel reduces them (the 256B graph memset showed
//     42 us in rocprof). (b) dinv[src] factored out of the per-edge loop:
//     u_out[m] = dinv[m]*(sum_{e:src=m} w_in[dst] + w_in[m]) -> hist does
//     ONE gather per edge instead of two. (c) Wout staged in LDS.

#define FDIM 128
#define HSZ 12500          // nodes per LDS group (50 KB)
#define NBG 64             // blocks per group
#define NB_V0 512
#define S_FIX 16777216.0f
#define INV_S (1.0f / 16777216.0f)

// ---------------- main path: LDS-histogram scatter ----------------

__global__ void __launch_bounds__(1024)
hist_deg_kernel(const int* __restrict__ edges, int E, int e4, int N,
                int* __restrict__ partial) {
  __shared__ int h[HSZ];
  const int g = blockIdx.x / NBG;
  const int j = blockIdx.x - g * NBG;
  const int lo = g * HSZ;
  const int hi = min(N, lo + HSZ);
  const int hs = hi - lo;
  for (int i = threadIdx.x; i < hs; i += blockDim.x) h[i] = 0;
  __syncthreads();
  const int* dst = edges + E;
  const int4* dst4 = (const int4*)dst;
  for (int i = j * blockDim.x + threadIdx.x; i < e4; i += NBG * blockDim.x) {
    int4 d = dst4[i];
    if (d.x >= lo && d.x < hi) atomicAdd(&h[d.x - lo], 1);
    if (d.y >= lo && d.y < hi) atomicAdd(&h[d.y - lo], 1);
    if (d.z >= lo && d.z < hi) atomicAdd(&h[d.z - lo], 1);
    if (d.w >= lo && d.w < hi) atomicAdd(&h[d.w - lo], 1);
  }
  if (j == 0) {
    for (int e = 4 * e4 + threadIdx.x; e < E; e += blockDim.x) {
      int d = dst[e];
      if (d >= lo && d < hi) atomicAdd(&h[d - lo], 1);
    }
  }
  __syncthreads();
  int* out = partial + (size_t)blockIdx.x * HSZ;
  for (int i = threadIdx.x; i < hs; i += blockDim.x) out[i] = h[i];
}

__global__ void merge_dinv_kernel(const int* __restrict__ partial,
                                  float* __restrict__ dinv, int N) {
  int n = blockIdx.x * blockDim.x + threadIdx.x;
  if (n >= N) return;
  int g = n / HSZ;
  int off = n - g * HSZ;
  const int* p = partial + ((size_t)g * NBG) * HSZ + off;
  int s = 1;                                  // self loop
  for (int jj = 0; jj < NBG; ++jj) s += p[(size_t)jj * HSZ];
  dinv[n] = rsqrtf((float)s);
}

// LDS-hist scatter of w[dst] onto src (dinv[src] applied at merge)
__global__ void __launch_bounds__(1024)
hist_u_kernel(const int* __restrict__ edges, int E, int e4, int N,
              const float* __restrict__ w,
              float* __restrict__ partial) {
  __shared__ float h[HSZ];
  const int g = blockIdx.x / NBG;
  const int j = blockIdx.x - g * NBG;
  const int lo = g * HSZ;
  const int hi = min(N, lo + HSZ);
  const int hs = hi - lo;
  for (int i = threadIdx.x; i < hs; i += blockDim.x) h[i] = 0.f;
  __syncthreads();
  const int4* s4 = (const int4*)edges;
  const int4* d4 = (const int4*)(edges + E);
  for (int i = j * blockDim.x + threadIdx.x; i < e4; i += NBG * blockDim.x) {
    int4 s = s4[i];
    int4 d = d4[i];
    if (s.x >= lo && s.x < hi) atomicAdd(&h[s.x - lo], w[d.x]);
    if (s.y >= lo && s.y < hi) atomicAdd(&h[s.y - lo], w[d.y]);
    if (s.z >= lo && s.z < hi) atomicAdd(&h[s.z - lo], w[d.z]);
    if (s.w >= lo && s.w < hi) atomicAdd(&h[s.w - lo], w[d.w]);
  }
  if (j == 0) {
    const int* se = edges; const int* de = edges + E;
    for (int e = 4 * e4 + threadIdx.x; e < E; e += blockDim.x) {
      int s = se[e], d = de[e];
      if (s >= lo && s < hi) atomicAdd(&h[s - lo], w[d]);
    }
  }
  __syncthreads();
  float* out = partial + (size_t)blockIdx.x * HSZ;
  for (int i = threadIdx.x; i < hs; i += blockDim.x) out[i] = h[i];
}

// u[n] = dinv[n]*(sum_j partial[j][n] + win[n]); optional uout/wout;
// per-block sum of u written to ssump[blockIdx] (no atomics, no memset).
__global__ void __launch_bounds__(256)
merge_u_kernel(const float* __restrict__ partial,
               const float* __restrict__ dinv,
               const float* __restrict__ win,
               float* __restrict__ uout,
               float* __restrict__ wout,
               float* __restrict__ ssump, int N) {
  __shared__ float red[4];
  int n = blockIdx.x * blockDim.x + threadIdx.x;
  float u = 0.f;
  if (n < N) {
    int g = n / HSZ;
    int off = n - g * HSZ;
    const float* p = partial + ((size_t)g * NBG) * HSZ + off;
    float s = 0.f;
    for (int jj = 0; jj < NBG; ++jj) s += p[(size_t)jj * HSZ];
    u = dinv[n] * (s + win[n]);               // self loop folded in
    if (uout) uout[n] = u;
    if (wout) wout[n] = dinv[n] * u;
  }
  if (ssump) {
    float a = u;
    for (int o = 32; o > 0; o >>= 1) a += __shfl_down(a, o, 64);
    if ((threadIdx.x & 63) == 0) red[threadIdx.x >> 6] = a;
    __syncthreads();
    if (threadIdx.x == 0)
      ssump[blockIdx.x] = red[0] + red[1] + red[2] + red[3];
  }
}

// per-block partials of v0[f] = sum_j u0[j]*feat[j][f]
__global__ void v0_kernel(const float* __restrict__ feat,
                          const float* __restrict__ u0,
                          float* __restrict__ v0p, int N) {
  __shared__ float sh[2][FDIM];
  int f = threadIdx.x & (FDIM - 1);
  int r2 = threadIdx.x >> 7;
  float acc = 0.f;
  for (int r = blockIdx.x * 2 + r2; r < N; r += gridDim.x * 2)
    acc += u0[r] * feat[(size_t)r * FDIM + f];
  sh[r2][f] = acc;
  __syncthreads();
  if (r2 == 0) v0p[(size_t)blockIdx.x * FDIM + f] = sh[0][f] + sh[1][f];
}

// 1024-thread tail: reduce v0p + ssum partials, 3 matvecs (W in LDS), head
__global__ void __launch_bounds__(1024)
final_kernel(const float* __restrict__ W0, const float* __restrict__ b0,
             const float* __restrict__ W1, const float* __restrict__ b1,
             const float* __restrict__ W2, const float* __restrict__ b2,
             const float* __restrict__ Wout, const float* __restrict__ bout,
             const float* __restrict__ v0p, int nv0,
             const float* __restrict__ ssumpA,  // partials of sum(u2)
             const float* __restrict__ ssumpB,  // partials of sum(u1)
             int nss,
             float* __restrict__ out, int N) {
  __shared__ float Wl[FDIM * FDIM];          // 64 KB
  __shared__ float WoL[FDIM * 10];           // 5 KB
  __shared__ float va[FDIM], vb[FDIM];
  __shared__ float part[8][FDIM];
  __shared__ float red0[16], red1[16];
  __shared__ float shS1, shS2;               // sum u1, sum u2
  __shared__ float lg[10];
  const int t = threadIdx.x;
  const int f = t & (FDIM - 1);
  const int sl = t >> 7;                     // 0..7

  // stage W0 + Wout into LDS (pipelines with the reductions below)
  {
    const float4* w4 = (const float4*)W0;
    float4* l4 = (float4*)Wl;
    #pragma unroll
    for (int i = 0; i < 4; ++i) l4[t + i * 1024] = w4[t + i * 1024];
    if (t < (FDIM * 10) / 4) ((float4*)WoL)[t] = ((const float4*)Wout)[t];
  }
  // reduce v0p: 8 slices of rows
  float acc = 0.f;
  for (int j = sl; j < nv0; j += 8) acc += v0p[(size_t)j * FDIM + f];
  part[sl][f] = acc;
  // reduce ssum partials (all 16 waves contribute)
  {
    float a0 = 0.f, a1 = 0.f;
    for (int j = t; j < nss; j += 1024) { a0 += ssumpA[j]; a1 += ssumpB[j]; }
    for (int o = 32; o > 0; o >>= 1) {
      a0 += __shfl_down(a0, o, 64);
      a1 += __shfl_down(a1, o, 64);
    }
    if ((t & 63) == 0) { red0[t >> 6] = a0; red1[t >> 6] = a1; }
  }
  __syncthreads();
  if (sl == 0) {
    float s = 0.f;
    #pragma unroll
    for (int j = 0; j < 8; ++j) s += part[j][f];
    va[f] = s;
  }
  if (t == 0) {
    float x = 0.f, y = 0.f;
    #pragma unroll
    for (int i = 0; i < 16; ++i) { x += red0[i]; y += red1[i]; }
    shS2 = x; shS1 = y;
  }
  __syncthreads();

  // vb = va@W0 + s1*b0
  acc = 0.f;
  #pragma unroll
  for (int k = 0; k < 16; ++k) {
    int kk = sl * 16 + k;
    acc += va[kk] * Wl[kk * FDIM + f];
  }
  part[sl][f] = acc;
  __syncthreads();                            // all Wl(W0) reads done
  {
    const float4* w4 = (const float4*)W1;     // stage W1
    float4* l4 = (float4*)Wl;
    #pragma unroll
    for (int i = 0; i < 4; ++i) l4[t + i * 1024] = w4[t + i * 1024];
  }
  if (sl == 0) {
    float s = 0.f;
    #pragma unroll
    for (int j = 0; j < 8; ++j) s += part[j][f];
    vb[f] = s + shS1 * b0[f];
  }
  __syncthreads();

  // va = vb@W1 + s2*b1
  acc = 0.f;
  #pragma unroll
  for (int k = 0; k < 16; ++k) {
    int kk = sl * 16 + k;
    acc += vb[kk] * Wl[kk * FDIM + f];
  }
  part[sl][f] = acc;
  __syncthreads();
  {
    const float4* w4 = (const float4*)W2;     // stage W2
    float4* l4 = (float4*)Wl;
    #pragma unroll
    for (int i = 0; i < 4; ++i) l4[t + i * 1024] = w4[t + i * 1024];
  }
  if (sl == 0) {
    float s = 0.f;
    #pragma unroll
    for (int j = 0; j < 8; ++j) s += part[j][f];
    va[f] = s + shS2 * b1[f];
  }
  __syncthreads();

  // vb = (va@W2)/N + b2  (= pooled)
  acc = 0.f;
  #pragma unroll
  for (int k = 0; k < 16; ++k) {
    int kk = sl * 16 + k;
    acc += va[kk] * Wl[kk * FDIM + f];
  }
  part[sl][f] = acc;
  __syncthreads();
  if (sl == 0) {
    float s = 0.f;
    #pragma unroll
    for (int j = 0; j < 8; ++j) s += part[j][f];
    vb[f] = s / (float)N + b2[f];
  }
  __syncthreads();

  if (t < 10) {
    float a = 0.f;
    for (int k = 0; k < FDIM; ++k) a += vb[k] * WoL[k * 10 + t];
    lg[t] = a + bout[t];
  }
  __syncthreads();
  if (t == 0) {
    float m = lg[0];
    for (int q = 1; q < 10; ++q) m = fmaxf(m, lg[q]);
    float s = 0.f;
    for (int q = 0; q < 10; ++q) s += expf(lg[q] - m);
    float lse = logf(s);
    for (int q = 0; q < 10; ++q) out[q] = lg[q] - m - lse;
  }
}

// ---------------- fallback path (R2, proven): global atomics ----------------

__global__ void deg_kernel(const int* __restrict__ edges, int E, int M,
                           int* __restrict__ deg) {
  for (int e = blockIdx.x * blockDim.x + threadIdx.x; e < M;
       e += gridDim.x * blockDim.x) {
    int d = (e < E) ? edges[E + e] : (e - E);
    atomicAdd(&deg[d], 1);
  }
}

__global__ void dinv_kernel(const int* __restrict__ deg,
                            float* __restrict__ dinv, int N) {
  int i = blockIdx.x * blockDim.x + threadIdx.x;
  if (i < N) {
    float d = (float)deg[i];
    dinv[i] = (d > 0.f) ? rsqrtf(d) : 0.f;
  }
}

__global__ void upass_kernel(const int* __restrict__ edges, int E, int M,
                             const float* __restrict__ dinv,
                             const int* __restrict__ uin_q,
                             int* __restrict__ uout_q) {
  for (int e = blockIdx.x * blockDim.x + threadIdx.x; e < M;
       e += gridDim.x * blockDim.x) {
    int s, d;
    if (e < E) { s = edges[e]; d = edges[E + e]; }
    else       { s = e - E;    d = s; }
    float v = dinv[s] * dinv[d];
    if (uin_q) v *= (float)uin_q[d] * INV_S;
    atomicAdd(&uout_q[s], __float2int_rn(v * S_FIX));
  }
}

__global__ void sums_kernel(const int* __restrict__ u2q,
                            const int* __restrict__ u1q,
                            float* __restrict__ ssump, int N) {
  __shared__ float red[8];
  int i = blockIdx.x * blockDim.x + threadIdx.x;
  float a = 0.f, b = 0.f;
  if (i < N) { a = (float)u2q[i] * INV_S; b = (float)u1q[i] * INV_S; }
  for (int o = 32; o > 0; o >>= 1) {
    a += __shfl_down(a, o, 64);
    b += __shfl_down(b, o, 64);
  }
  if ((threadIdx.x & 63) == 0) {
    red[(threadIdx.x >> 6) * 2] = a;
    red[(threadIdx.x >> 6) * 2 + 1] = b;
  }
  __syncthreads();
  if (threadIdx.x == 0) {
    ssump[blockIdx.x] = red[0] + red[2] + red[4] + red[6];
    ssump[gridDim.x + blockIdx.x] = red[1] + red[3] + red[5] + red[7];
  }
}

__global__ void v0_fallback_kernel(const float* __restrict__ feat,
                                   const int* __restrict__ u0q,
                                   float* __restrict__ v0p, int N) {
  __shared__ float sh[2][FDIM];
  int f = threadIdx.x & (FDIM - 1);
  int r2 = threadIdx.x >> 7;
  float acc = 0.f;
  for (int r = blockIdx.x * 2 + r2; r < N; r += gridDim.x * 2)
    acc += ((float)u0q[r] * INV_S) * feat[(size_t)r * FDIM + f];
  sh[r2][f] = acc;
  __syncthreads();
  if (r2 == 0) v0p[(size_t)blockIdx.x * FDIM + f] = sh[0][f] + sh[1][f];
}

// ---------------- launch ----------------

extern "C" void kernel_launch(void* const* d_in, const int* in_sizes, int n_in,
                              void* d_out, int out_size, void* d_ws, size_t ws_size,
                              hipStream_t stream) {
  const float* feat = (const float*)d_in[0];
  const int*   edges = (const int*)d_in[1];
  const float* W0 = (const float*)d_in[2];
  const float* b0 = (const float*)d_in[3];
  const float* W1 = (const float*)d_in[4];
  const float* b1 = (const float*)d_in[5];
  const float* W2 = (const float*)d_in[6];
  const float* b2 = (const float*)d_in[7];
  const float* Wout = (const float*)d_in[8];
  const float* bout = (const float*)d_in[9];

  const int N = in_sizes[0] / FDIM;          // 50000
  const int E = in_sizes[1] / 2;             // 1.6M
  const int NG = (N + HSZ - 1) / HSZ;        // 4 groups
  const int e4 = ((E & 3) == 0) ? (E >> 2) : 0;
  const int mergeGrid = (N + 255) / 256;     // 196

  char* ws = (char*)d_ws;
  size_t nb = ((size_t)N * 4 + 511) & ~(size_t)511;
  size_t partB = ((size_t)NG * NBG * HSZ * 4 + 511) & ~(size_t)511;
  size_t v0pB = (size_t)NB_V0 * FDIM * 4;
  size_t ssB = ((size_t)mergeGrid * 4 + 511) & ~(size_t)511;
  size_t need = partB + 4 * nb + v0pB + 2 * ssB;

  if (ws_size >= need) {
    // main path — no memsets, no device-scope atomics
    char* p = ws;
    void*  part = (void*)p;        p += partB;
    float* dinv = (float*)p;       p += nb;
    float* w2   = (float*)p;       p += nb;
    float* w1   = (float*)p;       p += nb;
    float* u0   = (float*)p;       p += nb;
    float* v0p  = (float*)p;       p += v0pB;
    float* ssA  = (float*)p;       p += ssB;   // per-block partials of sum u2
    float* ssB_ = (float*)p;                   // per-block partials of sum u1

    hist_deg_kernel<<<NG * NBG, 1024, 0, stream>>>(edges, E, e4, N, (int*)part);
    merge_dinv_kernel<<<mergeGrid, 256, 0, stream>>>((const int*)part, dinv, N);
    hist_u_kernel<<<NG * NBG, 1024, 0, stream>>>(edges, E, e4, N, dinv, (float*)part);
    merge_u_kernel<<<mergeGrid, 256, 0, stream>>>((const float*)part, dinv, dinv,
                                                  nullptr, w2, ssA, N);
    hist_u_kernel<<<NG * NBG, 1024, 0, stream>>>(edges, E, e4, N, w2, (float*)part);
    merge_u_kernel<<<mergeGrid, 256, 0, stream>>>((const float*)part, dinv, w2,
                                                  nullptr, w1, ssB_, N);
    hist_u_kernel<<<NG * NBG, 1024, 0, stream>>>(edges, E, e4, N, w1, (float*)part);
    merge_u_kernel<<<mergeGrid, 256, 0, stream>>>((const float*)part, dinv, w1,
                                                  u0, nullptr, nullptr, N);
    v0_kernel<<<NB_V0, 256, 0, stream>>>(feat, u0, v0p, N);
    final_kernel<<<1, 1024, 0, stream>>>(W0, b0, W1, b1, W2, b2, Wout, bout,
                                         v0p, NB_V0, ssA, ssB_, mergeGrid,
                                         (float*)d_out, N);
  } else {
    // fallback (R2-style): global-atomic scatter, no memset except accumulators
    const int M = E + N;
    int*   deg  = (int*)(ws);
    float* dinv = (float*)(ws + nb);
    int*   u2q  = (int*)(ws + 2 * nb);
    int*   u1q  = (int*)(ws + 3 * nb);
    int*   u0q  = (int*)(ws + 4 * nb);
    float* v0p  = (float*)(ws + 5 * nb);               // NB_V0*FDIM
    float* ssp  = (float*)(ws + 5 * nb + v0pB);        // 2*mergeGrid

    hipMemsetAsync(ws, 0, 5 * nb, stream);

    deg_kernel<<<2048, 256, 0, stream>>>(edges, E, M, deg);
    dinv_kernel<<<mergeGrid, 256, 0, stream>>>(deg, dinv, N);
    upass_kernel<<<2048, 256, 0, stream>>>(edges, E, M, dinv, nullptr, u2q);
    upass_kernel<<<2048, 256, 0, stream>>>(edges, E, M, dinv, u2q, u1q);
    upass_kernel<<<2048, 256, 0, stream>>>(edges, E, M, dinv, u1q, u0q);
    sums_kernel<<<mergeGrid, 256, 0, stream>>>(u2q, u1q, ssp, N);
    v0_fallback_kernel<<<NB_V0, 256, 0, stream>>>(feat, u0q, v0p, N);
    final_kernel<<<1, 1024, 0, stream>>>(W0, b0, W1, b1, W2, b2, Wout, bout,
                                         v0p, NB_V0, ssp, ssp + mergeGrid,
                                         mergeGrid, (float*)d_out, N);
  }
}